// Round 10
// baseline (101.066 us; speedup 1.0000x reference)
//
#include <hip/hip_runtime.h>

// LSTM (B=131072, T=24, input=3, H=32) + Linear(32,16)+ReLU+Linear(16,1)
//
// gates^T = Whh * h^T (mfma 16x16x32 f16) + Wib * [x;1]^T (mfma 16x16x16 f16).
// TWO streams/wave (R8's winning interleave) but Phase A->B per stream
// SEQUENTIALLY: only one stream's 32 acc regs live at once -> total regs
// ~120 <= 128 -> 4 waves/SIMD (R8 had 148 -> 2 waves). Stream s+1's MFMA
// burst overlaps stream s's trans burst on separate pipes. sig(o) exps
// hoisted into the main trans burst. Unit->row permutation keeps h lane-
// local (no cross-lane traffic, no per-step barrier). Weights prescaled by
// log2e (2*log2e for g); c-state in 2*log2e domain. FP16 storage (R5).

typedef _Float16 f16x8 __attribute__((ext_vector_type(8)));
typedef _Float16 f16x4 __attribute__((ext_vector_type(4)));
typedef _Float16 f16x2 __attribute__((ext_vector_type(2)));
typedef float f32x4 __attribute__((ext_vector_type(4)));
typedef float f32x2 __attribute__((ext_vector_type(2)));

#define L2E 1.4426950408889634f

#if __has_builtin(__builtin_amdgcn_mfma_f32_16x16x16f16)
#define HAVE_MFMA16 1
#else
#define HAVE_MFMA16 0
#endif

__device__ __forceinline__ float fexp2(float v) { return __builtin_amdgcn_exp2f(v); }
__device__ __forceinline__ float frcp(float v)  { return __builtin_amdgcn_rcpf(v); }

__global__ __launch_bounds__(256, 4)
void lstm_fused(const float* __restrict__ x,
                const float* __restrict__ w_ih,
                const float* __restrict__ w_hh,
                const float* __restrict__ b_ih,
                const float* __restrict__ b_hh,
                const float* __restrict__ w1,
                const float* __restrict__ b1,
                const float* __restrict__ w2,
                const float* __restrict__ b2,
                float* __restrict__ out)
{
    __shared__ int2  xq[24 * 128];  // [t][n] packed f16 {x0,x1,x2,1.0} (24 KB)
    __shared__ float w1s[512];
    __shared__ float b1s[16];
    __shared__ float w2s[16];
    __shared__ float b2s;

    const int tid  = threadIdx.x;
    const int lane = tid & 63;
    const int wv   = tid >> 6;      // wave id 0..3
    const int c    = lane & 15;     // batch column within wave tile
    const int g    = lane >> 4;     // k-group 0..3
    const int blockBase = blockIdx.x * 128;

    for (int i = tid; i < 512; i += 256) w1s[i] = w1[i];
    if (tid < 16) { b1s[tid] = b1[tid]; w2s[tid] = w2[tid]; }
    if (tid == 16) b2s = b2[0];

    // ---- stage x: pack (x0,x1,x2,1.0) as f16 per (row, t) ----
    for (int it = 0; it < 12; ++it) {
        int p = tid + it * 256;          // 0..3071 = 128 rows * 24 steps
        int n = p / 24;
        int t = p - n * 24;
        const float* xp = x + ((blockBase + n) * 24 + t) * 3;
        union { f16x4 h; int2 i2; } tq;
        tq.h[0] = (_Float16)xp[0];
        tq.h[1] = (_Float16)xp[1];
        tq.h[2] = (_Float16)xp[2];
        tq.h[3] = (_Float16)1.0f;        // hits fused-bias column
        xq[t * 128 + n] = tq.i2;
    }

    // ---- preload weight A-frags (wave-uniform, permuted rows, prescaled) ----
    // MFMA (G,p) row r computes unit(r,p) = 8*(r>>2) + 4p + (r&3).
    // whh element e = W[row=c][k = 8g+e]; wib element e = k = 4g+e (K=16 frag).
    f16x8 whh[8];
#if HAVE_MFMA16
    f16x4 wib[8];
#else
    f16x8 wib[8];
#endif
    const int ubase = 8 * (c >> 2) + (c & 3);
#pragma unroll
    for (int G = 0; G < 4; ++G) {
        const float scale = (G == 2) ? (2.f * L2E) : L2E;
#pragma unroll
        for (int p = 0; p < 2; ++p) {
            const int row = G * 32 + ubase + 4 * p;
            const float* wr = w_hh + row * 32 + g * 8;
            f16x8 a;
#pragma unroll
            for (int e = 0; e < 8; ++e) a[e] = (_Float16)(wr[e] * scale);
            whh[G * 2 + p] = a;
            _Float16 c0 = 0, c1 = 0, c2 = 0, c3 = 0;
            if (g == 0) {
                c0 = (_Float16)(w_ih[row * 3 + 0] * scale);
                c1 = (_Float16)(w_ih[row * 3 + 1] * scale);
                c2 = (_Float16)(w_ih[row * 3 + 2] * scale);
                c3 = (_Float16)((b_ih[row] + b_hh[row]) * scale);
            }
#if HAVE_MFMA16
            f16x4 bb = {c0, c1, c2, c3};
#else
            f16x8 bb = {c0, c1, c2, c3, 0, 0, 0, 0};
#endif
            wib[G * 2 + p] = bb;
        }
    }

    __syncthreads();   // xq/w1s staged (only barrier in the kernel)

    // ---- two independent batch streams per wave ----
    f32x2 cz = {0.f, 0.f};
    f32x2 cst2[8];                        // [s*4 + p*2 + j]
#pragma unroll
    for (int q = 0; q < 8; ++q) cst2[q] = cz;
    union hu_t { f16x2 p2[4]; f16x8 v; int4 i4; } hreg[2];
    hreg[0].i4 = make_int4(0, 0, 0, 0);
    hreg[1].i4 = make_int4(0, 0, 0, 0);

    const int n0 = wv * 16 + c;          // stream 0 column; stream 1: +64
    int2 xv[2];
    xv[0] = xq[n0];
    xv[1] = xq[n0 + 64];

#pragma unroll 1
    for (int t = 0; t < 24; ++t) {
        const int tn = (t < 23) ? t + 1 : 23;
        int2 xn0 = xq[tn * 128 + n0];        // prefetch next step
        int2 xn1 = xq[tn * 128 + n0 + 64];

#pragma unroll
        for (int s = 0; s < 2; ++s) {
            // ---- Phase A: 16 MFMAs for THIS stream (32 live acc regs) ----
            f32x4 acc[2][4];                 // [p][gate]
            const f32x4 z = {0.f, 0.f, 0.f, 0.f};
            f16x8 hf = hreg[s].v;
#pragma unroll
            for (int p = 0; p < 2; ++p)
#pragma unroll
                for (int G = 0; G < 4; ++G)
                    acc[p][G] = __builtin_amdgcn_mfma_f32_16x16x32_f16(
                        whh[2 * G + p], hf, z, 0, 0, 0);
            {
                int xlo = (g == 0) ? xv[s].x : 0;
                int xhi = (g == 0) ? xv[s].y : 0;
#if HAVE_MFMA16
                union { int2 i2; f16x4 v; } xu;
                xu.i2 = make_int2(xlo, xhi);
                f16x4 xf = xu.v;
#else
                union { int4 i4; f16x8 v; } xu;
                xu.i4 = make_int4(xlo, xhi, 0, 0);
                f16x8 xf = xu.v;
#endif
#pragma unroll
                for (int p = 0; p < 2; ++p)
#pragma unroll
                    for (int G = 0; G < 4; ++G)
#if HAVE_MFMA16
                        acc[p][G] = __builtin_amdgcn_mfma_f32_16x16x16f16(
                            wib[2 * G + p], xf, acc[p][G], 0, 0, 0);
#else
                        acc[p][G] = __builtin_amdgcn_mfma_f32_16x16x32_f16(
                            wib[2 * G + p], xf, acc[p][G], 0, 0, 0);
#endif
            }

            // ---- Phase B: stage-parallel activation, 4 pair-chains ----
            f32x2 ew[4];
#pragma unroll
            for (int q = 0; q < 4; ++q) {    // off-critical-path sig(o) exps
                const int p = q >> 1, j = q & 1;
                ew[q][0] = fexp2(-acc[p][3][2 * j]);
                ew[q][1] = fexp2(-acc[p][3][2 * j + 1]);
            }
            f32x2 ex[4], ey[4], ef[4];
#pragma unroll
            for (int q = 0; q < 4; ++q) {    // stage 1: i/g/f exps
                const int p = q >> 1, j = q & 1;
                ex[q][0] = fexp2(-acc[p][0][2 * j]); ex[q][1] = fexp2(-acc[p][0][2 * j + 1]);
                ey[q][0] = fexp2( acc[p][2][2 * j]); ey[q][1] = fexp2( acc[p][2][2 * j + 1]);
                ef[q][0] = fexp2(-acc[p][1][2 * j]); ef[q][1] = fexp2(-acc[p][1][2 * j + 1]);
            }
            const f32x2 one = {1.f, 1.f};
            const f32x2 K2  = {2.f * L2E, 2.f * L2E};
            f32x2 axy[4], efp[4], r1[4];
#pragma unroll
            for (int q = 0; q < 4; ++q) {    // stage 2: denominators + rcp
                axy[q] = (one + ex[q]) * (one + ey[q]);
                efp[q] = one + ef[q];
                f32x2 dd = axy[q] * efp[q];
                r1[q][0] = frcp(dd[0]); r1[q][1] = frcp(dd[1]);
            }
            f32x2 ez[4];
#pragma unroll
            for (int q = 0; q < 4; ++q) {    // stage 3: c update + exp2
                f32x2 igs = (ey[q] * K2 - K2) * efp[q] * r1[q];
                f32x2 fs  = axy[q] * r1[q];
                cst2[s * 4 + q] = fs * cst2[s * 4 + q] + igs;
                ez[q][0] = fexp2(cst2[s * 4 + q][0]);
                ez[q][1] = fexp2(cst2[s * 4 + q][1]);
            }
#pragma unroll
            for (int q = 0; q < 4; ++q) {    // stage 4: h = sig(o)*tanh(c)
                f32x2 d2 = (one + ew[q]) * (one + ez[q]);
                f32x2 r2; r2[0] = frcp(d2[0]); r2[1] = frcp(d2[1]);
                f32x2 hn = (ez[q] - one) * r2;
                f16x2 hh; hh[0] = (_Float16)hn[0]; hh[1] = (_Float16)hn[1];
                hreg[s].p2[q] = hh;
            }
        }
        xv[0] = xn0;
        xv[1] = xn1;
    }

    // ---- head: lane (c,g) holds h[8g..8g+7] of batch cols n0, n0+64 ----
#pragma unroll
    for (int s = 0; s < 2; ++s) {
        float hfin[8];
#pragma unroll
        for (int d = 0; d < 8; ++d) hfin[d] = (float)hreg[s].v[d];
        float hid[16];
#pragma unroll
        for (int q = 0; q < 16; ++q) {
            const float4* wrow = (const float4*)(w1s + q * 32 + g * 8);
            float4 wa = wrow[0], wb = wrow[1];
            float sm = wa.x * hfin[0] + wa.y * hfin[1] + wa.z * hfin[2] + wa.w * hfin[3]
                     + wb.x * hfin[4] + wb.y * hfin[5] + wb.z * hfin[6] + wb.w * hfin[7];
            sm += __shfl_xor(sm, 16);
            sm += __shfl_xor(sm, 32);
            hid[q] = sm;
        }
        float po = b2s;
#pragma unroll
        for (int q = 0; q < 16; ++q)
            po = fmaf(fmaxf(hid[q] + b1s[q], 0.f), w2s[q], po);
        if (g == 0) out[blockBase + s * 64 + n0] = po;
    }
}

extern "C" void kernel_launch(void* const* d_in, const int* in_sizes, int n_in,
                              void* d_out, int out_size, void* d_ws, size_t ws_size,
                              hipStream_t stream) {
    (void)in_sizes; (void)n_in; (void)d_ws; (void)ws_size; (void)out_size;
    const float* x    = (const float*)d_in[0];
    const float* w_ih = (const float*)d_in[1];
    const float* w_hh = (const float*)d_in[2];
    const float* b_ih = (const float*)d_in[3];
    const float* b_hh = (const float*)d_in[4];
    const float* w1   = (const float*)d_in[5];
    const float* b1   = (const float*)d_in[6];
    const float* w2   = (const float*)d_in[7];
    const float* b2   = (const float*)d_in[8];
    float* outp = (float*)d_out;

    dim3 grid(131072 / 128);   // 128 rows per block (4 waves x 16 x 2 streams)
    dim3 block(256);
    hipLaunchKernelGGL(lstm_fused, grid, block, 0, stream,
                       x, w_ih, w_hh, b_ih, b_hh, w1, b1, w2, b2, outp);
}

// Round 11
// 95.552 us; speedup vs baseline: 1.0577x; 1.0577x over previous
//
#include <hip/hip_runtime.h>

// LSTM (B=131072, T=24, input=3, H=32) + Linear(32,16)+ReLU+Linear(16,1)
//
// gates^T = Whh * h^T (mfma 16x16x32 f16) + Wib * [x;1]^T (mfma 16x16x16 f16).
// TWO streams/wave, MODULO-SCHEDULED: body = { MFMA_B(t); ACT_A(t); ACT_B(t);
// MFMA_A(t+1) } with MFMA_A(0) peeled into a prologue and t=23 peeled into an
// epilogue. Each ACT sits between two independent MFMA blocks -> the serial
// activation tail (c-fma->exp2->rcp->pack) of one stream is covered by the
// other stream's MFMAs, and MFMA latency is covered by the ~400cy ACT. Only
// one acc set is fully live at a time -> ~140 regs -> 3 waves/SIMD (R8's
// all-MFMAs-first form needed 2x32 acc live and fell to 2 waves/SIMD).
// Unit->row permutation keeps h lane-local (no cross-lane traffic, no
// per-step barrier). Weights prescaled by log2e (2*log2e for g); c-state in
// 2*log2e domain so ez=exp2(cs). FP16 storage for h/w/x (R5 lesson).

typedef _Float16 f16x8 __attribute__((ext_vector_type(8)));
typedef _Float16 f16x4 __attribute__((ext_vector_type(4)));
typedef _Float16 f16x2 __attribute__((ext_vector_type(2)));
typedef float f32x4 __attribute__((ext_vector_type(4)));
typedef float f32x2 __attribute__((ext_vector_type(2)));

#define L2E 1.4426950408889634f

#if __has_builtin(__builtin_amdgcn_mfma_f32_16x16x16f16)
#define HAVE_MFMA16 1
#else
#define HAVE_MFMA16 0
#endif

__device__ __forceinline__ float fexp2(float v) { return __builtin_amdgcn_exp2f(v); }
__device__ __forceinline__ float frcp(float v)  { return __builtin_amdgcn_rcpf(v); }

__global__ __launch_bounds__(256, 3)
void lstm_fused(const float* __restrict__ x,
                const float* __restrict__ w_ih,
                const float* __restrict__ w_hh,
                const float* __restrict__ b_ih,
                const float* __restrict__ b_hh,
                const float* __restrict__ w1,
                const float* __restrict__ b1,
                const float* __restrict__ w2,
                const float* __restrict__ b2,
                float* __restrict__ out)
{
    __shared__ int2  xq[24 * 128];  // [t][n] packed f16 {x0,x1,x2,1.0} (24 KB)
    __shared__ float w1s[512];
    __shared__ float b1s[16];
    __shared__ float w2s[16];
    __shared__ float b2s;

    const int tid  = threadIdx.x;
    const int lane = tid & 63;
    const int wv   = tid >> 6;      // wave id 0..3
    const int c    = lane & 15;     // batch column within wave tile
    const int g    = lane >> 4;     // k-group 0..3
    const int blockBase = blockIdx.x * 128;

    for (int i = tid; i < 512; i += 256) w1s[i] = w1[i];
    if (tid < 16) { b1s[tid] = b1[tid]; w2s[tid] = w2[tid]; }
    if (tid == 16) b2s = b2[0];

    // ---- stage x: pack (x0,x1,x2,1.0) as f16 per (row, t) ----
    for (int it = 0; it < 12; ++it) {
        int p = tid + it * 256;          // 0..3071 = 128 rows * 24 steps
        int n = p / 24;
        int t = p - n * 24;
        const float* xp = x + ((blockBase + n) * 24 + t) * 3;
        union { f16x4 h; int2 i2; } tq;
        tq.h[0] = (_Float16)xp[0];
        tq.h[1] = (_Float16)xp[1];
        tq.h[2] = (_Float16)xp[2];
        tq.h[3] = (_Float16)1.0f;        // hits fused-bias column
        xq[t * 128 + n] = tq.i2;
    }

    // ---- preload weight A-frags (wave-uniform, permuted rows, prescaled) ----
    // MFMA (G,p) row r computes unit(r,p) = 8*(r>>2) + 4p + (r&3).
    // whh element e = W[row=c][k = 8g+e]; wib element e = k = 4g+e (K=16 frag).
    f16x8 whh[8];
#if HAVE_MFMA16
    f16x4 wib[8];
#else
    f16x8 wib[8];
#endif
    const int ubase = 8 * (c >> 2) + (c & 3);
#pragma unroll
    for (int G = 0; G < 4; ++G) {
        const float scale = (G == 2) ? (2.f * L2E) : L2E;
#pragma unroll
        for (int p = 0; p < 2; ++p) {
            const int row = G * 32 + ubase + 4 * p;
            const float* wr = w_hh + row * 32 + g * 8;
            f16x8 a;
#pragma unroll
            for (int e = 0; e < 8; ++e) a[e] = (_Float16)(wr[e] * scale);
            whh[G * 2 + p] = a;
            _Float16 c0 = 0, c1 = 0, c2 = 0, c3 = 0;
            if (g == 0) {
                c0 = (_Float16)(w_ih[row * 3 + 0] * scale);
                c1 = (_Float16)(w_ih[row * 3 + 1] * scale);
                c2 = (_Float16)(w_ih[row * 3 + 2] * scale);
                c3 = (_Float16)((b_ih[row] + b_hh[row]) * scale);
            }
#if HAVE_MFMA16
            f16x4 bb = {c0, c1, c2, c3};
#else
            f16x8 bb = {c0, c1, c2, c3, 0, 0, 0, 0};
#endif
            wib[G * 2 + p] = bb;
        }
    }

    __syncthreads();   // xq/w1s staged (only barrier in the kernel)

    // ---- two independent batch streams per wave ----
    f32x2 cz = {0.f, 0.f};
    f32x2 cst2[8];                        // [s*4 + p*2 + j]
#pragma unroll
    for (int q = 0; q < 8; ++q) cst2[q] = cz;
    union hu_t { f16x2 p2[4]; f16x8 v; int4 i4; } hreg[2];
    hreg[0].i4 = make_int4(0, 0, 0, 0);
    hreg[1].i4 = make_int4(0, 0, 0, 0);

    const int n0 = wv * 16 + c;          // stream 0 column; stream 1: +64
    int2 xv[2];
    xv[0] = xq[n0];
    xv[1] = xq[n0 + 64];

    // 16 MFMAs for one stream's step into acc
    auto MFMA_STEP = [&](const f16x8& hf, const int2& xvs, f32x4 (&acc)[2][4]) {
        const f32x4 z = {0.f, 0.f, 0.f, 0.f};
#pragma unroll
        for (int p = 0; p < 2; ++p)
#pragma unroll
            for (int G = 0; G < 4; ++G)
                acc[p][G] = __builtin_amdgcn_mfma_f32_16x16x32_f16(
                    whh[2 * G + p], hf, z, 0, 0, 0);
        int xlo = (g == 0) ? xvs.x : 0;
        int xhi = (g == 0) ? xvs.y : 0;
#if HAVE_MFMA16
        union { int2 i2; f16x4 v; } xu;
        xu.i2 = make_int2(xlo, xhi);
        f16x4 xf = xu.v;
#else
        union { int4 i4; f16x8 v; } xu;
        xu.i4 = make_int4(xlo, xhi, 0, 0);
        f16x8 xf = xu.v;
#endif
#pragma unroll
        for (int p = 0; p < 2; ++p)
#pragma unroll
            for (int G = 0; G < 4; ++G)
#if HAVE_MFMA16
                acc[p][G] = __builtin_amdgcn_mfma_f32_16x16x16f16(
                    wib[2 * G + p], xf, acc[p][G], 0, 0, 0);
#else
                acc[p][G] = __builtin_amdgcn_mfma_f32_16x16x32_f16(
                    wib[2 * G + p], xf, acc[p][G], 0, 0, 0);
#endif
    };

    // stage-parallel activation for one stream (4 pair-chains)
    auto ACT_STEP = [&](f32x4 (&acc)[2][4], int sb, hu_t& hr) {
        f32x2 ew[4];
#pragma unroll
        for (int q = 0; q < 4; ++q) {    // off-critical-path sig(o) exps
            const int p = q >> 1, j = q & 1;
            ew[q][0] = fexp2(-acc[p][3][2 * j]);
            ew[q][1] = fexp2(-acc[p][3][2 * j + 1]);
        }
        f32x2 ex[4], ey[4], ef[4];
#pragma unroll
        for (int q = 0; q < 4; ++q) {    // stage 1: i/g/f exps
            const int p = q >> 1, j = q & 1;
            ex[q][0] = fexp2(-acc[p][0][2 * j]); ex[q][1] = fexp2(-acc[p][0][2 * j + 1]);
            ey[q][0] = fexp2( acc[p][2][2 * j]); ey[q][1] = fexp2( acc[p][2][2 * j + 1]);
            ef[q][0] = fexp2(-acc[p][1][2 * j]); ef[q][1] = fexp2(-acc[p][1][2 * j + 1]);
        }
        const f32x2 one = {1.f, 1.f};
        const f32x2 K2  = {2.f * L2E, 2.f * L2E};
        f32x2 axy[4], efp[4], r1[4];
#pragma unroll
        for (int q = 0; q < 4; ++q) {    // stage 2: denominators + rcp
            axy[q] = (one + ex[q]) * (one + ey[q]);
            efp[q] = one + ef[q];
            f32x2 dd = axy[q] * efp[q];
            r1[q][0] = frcp(dd[0]); r1[q][1] = frcp(dd[1]);
        }
        f32x2 ez[4];
#pragma unroll
        for (int q = 0; q < 4; ++q) {    // stage 3: c update + exp2
            f32x2 igs = (ey[q] * K2 - K2) * efp[q] * r1[q];
            f32x2 fs  = axy[q] * r1[q];
            cst2[sb + q] = fs * cst2[sb + q] + igs;
            ez[q][0] = fexp2(cst2[sb + q][0]);
            ez[q][1] = fexp2(cst2[sb + q][1]);
        }
#pragma unroll
        for (int q = 0; q < 4; ++q) {    // stage 4: h = sig(o)*tanh(c)
            f32x2 d2 = (one + ew[q]) * (one + ez[q]);
            f32x2 r2; r2[0] = frcp(d2[0]); r2[1] = frcp(d2[1]);
            f32x2 hn = (ez[q] - one) * r2;
            f16x2 hh; hh[0] = (_Float16)hn[0]; hh[1] = (_Float16)hn[1];
            hr.p2[q] = hh;
        }
    };

    f32x4 accA[2][4], accB[2][4];

    // prologue: stream A, t=0
    MFMA_STEP(hreg[0].v, xv[0], accA);

#pragma unroll 1
    for (int t = 0; t < 23; ++t) {
        int2 xn0 = xq[(t + 1) * 128 + n0];      // prefetch next step
        int2 xn1 = xq[(t + 1) * 128 + n0 + 64];

        MFMA_STEP(hreg[1].v, xv[1], accB);      // stream B, step t
        ACT_STEP(accA, 0, hreg[0]);             // h_A(t)  (covers MFMA_B exec)
        ACT_STEP(accB, 4, hreg[1]);             // h_B(t)
        xv[0] = xn0;
        xv[1] = xn1;
        MFMA_STEP(hreg[0].v, xv[0], accA);      // stream A, step t+1
    }
    // epilogue: t = 23
    MFMA_STEP(hreg[1].v, xv[1], accB);
    ACT_STEP(accA, 0, hreg[0]);
    ACT_STEP(accB, 4, hreg[1]);

    // ---- head: lane (c,g) holds h[8g..8g+7] of batch cols n0, n0+64 ----
#pragma unroll
    for (int s = 0; s < 2; ++s) {
        float hfin[8];
#pragma unroll
        for (int d = 0; d < 8; ++d) hfin[d] = (float)hreg[s].v[d];
        float hid[16];
#pragma unroll
        for (int q = 0; q < 16; ++q) {
            const float4* wrow = (const float4*)(w1s + q * 32 + g * 8);
            float4 wa = wrow[0], wb = wrow[1];
            float sm = wa.x * hfin[0] + wa.y * hfin[1] + wa.z * hfin[2] + wa.w * hfin[3]
                     + wb.x * hfin[4] + wb.y * hfin[5] + wb.z * hfin[6] + wb.w * hfin[7];
            sm += __shfl_xor(sm, 16);
            sm += __shfl_xor(sm, 32);
            hid[q] = sm;
        }
        float po = b2s;
#pragma unroll
        for (int q = 0; q < 16; ++q)
            po = fmaf(fmaxf(hid[q] + b1s[q], 0.f), w2s[q], po);
        if (g == 0) out[blockBase + s * 64 + n0] = po;
    }
}

extern "C" void kernel_launch(void* const* d_in, const int* in_sizes, int n_in,
                              void* d_out, int out_size, void* d_ws, size_t ws_size,
                              hipStream_t stream) {
    (void)in_sizes; (void)n_in; (void)d_ws; (void)ws_size; (void)out_size;
    const float* x    = (const float*)d_in[0];
    const float* w_ih = (const float*)d_in[1];
    const float* w_hh = (const float*)d_in[2];
    const float* b_ih = (const float*)d_in[3];
    const float* b_hh = (const float*)d_in[4];
    const float* w1   = (const float*)d_in[5];
    const float* b1   = (const float*)d_in[6];
    const float* w2   = (const float*)d_in[7];
    const float* b2   = (const float*)d_in[8];
    float* outp = (float*)d_out;

    dim3 grid(131072 / 128);   // 128 rows per block (4 waves x 16 x 2 streams)
    dim3 block(256);
    hipLaunchKernelGGL(lstm_fused, grid, block, 0, stream,
                       x, w_ih, w_hh, b_ih, b_hh, w1, b1, w2, b2, outp);
}